// Round 6
// baseline (340.162 us; speedup 1.0000x reference)
//
#include <hip/hip_runtime.h>

#define LOG2E 1.44269504088896340736f

typedef __attribute__((ext_vector_type(8))) short short8;
typedef __attribute__((ext_vector_type(4))) float f32x4;

constexpr int CL       = 10;              // layers per staged chunk
constexpr int LAYER_BY = 2048;            // bytes/layer: 2 tiles x 64 lanes x 16B
constexpr int CHUNK_BY = CL * LAYER_BY;   // 20480
constexpr int CHUNK_V4 = CHUNK_BY / 16;   // 1280 float4
constexpr int V4_PER_T = CHUNK_V4 / 256;  // 5 per thread

// k-slot -> logical input position (same mapping in prepack/A and runtime/B,
// so HW k-order cancels). pos 20 carries bias (B supplies 1.0).
__device__ __forceinline__ int slot_pos(int h, int e) {
    return (e < 4) ? (4 * h + e) : (16 + 4 * h + (e - 4));
}

__device__ __forceinline__ unsigned short f32_to_bf16_rne(float f) {
    unsigned u = __builtin_bit_cast(unsigned, f);
    unsigned r = 0x7fffu + ((u >> 16) & 1u);
    return (unsigned short)((u + r) >> 16);
}

// One block per layer; 128 threads = 2 tiles x 64 lanes. Weights and bias are
// PRE-SCALED by -log2e: acc = -log2e*(W h + b), so sigmoid = rcp(1+exp2(acc))
// needs no per-value multiply in the main loop.
__global__ void prepack(const float* __restrict__ W, const float* __restrict__ b,
                        unsigned int* __restrict__ wstream, int L)
{
    const int l    = blockIdx.x;
    const int t    = threadIdx.x >> 6;
    const int lane = threadIdx.x & 63;
    const int n    = t * 16 + (lane & 15);   // output-neuron position
    const int h    = lane >> 4;
    unsigned int words[4];
#pragma unroll
    for (int d = 0; d < 4; ++d) {
        unsigned short halves[2];
#pragma unroll
        for (int half = 0; half < 2; ++half) {
            int e   = d * 2 + half;
            int pos = slot_pos(h, e);
            float v = 0.f;
            if (n < 20) {
                if (pos < 20)       v = W[(size_t)l * 400 + n * 20 + pos];
                else if (pos == 20) v = b[(size_t)l * 20 + n];
            }
            halves[half] = f32_to_bf16_rne(v * -LOG2E);
        }
        words[d] = (unsigned)halves[0] | ((unsigned)halves[1] << 16);
    }
    unsigned int* dst = wstream + ((size_t)l * LAYER_BY + t * 1024 + lane * 16) / 4;
    dst[0] = words[0]; dst[1] = words[1]; dst[2] = words[2]; dst[3] = words[3];
}

__device__ __forceinline__ unsigned cvt_pk_bf16(float lo, float hi) {
    unsigned r;
    asm("v_cvt_pk_bf16_f32 %0, %1, %2" : "=v"(r) : "v"(lo), "v"(hi));
    return r;
}

// Mask pad slots: h==0 keeps real positions 16..19; h==1 slot e=4 is pos 20
// -> constant 1.0 (bias multiplier); rest of upper half is pad.
__device__ __forceinline__ short8 finalize_B(unsigned p0, unsigned p1,
                                             unsigned p2, unsigned p3, int h) {
    if (h != 0) { p2 = (h == 1) ? 0x00003F80u : 0u; p3 = 0u; }
    union { unsigned u[4]; short8 s; } cv;
    cv.u[0] = p0; cv.u[1] = p1; cv.u[2] = p2; cv.u[3] = p3;
    return cv.s;
}

// acc already = -log2e * z  (scale folded into weights)
__device__ __forceinline__ float sigm_pre(float a) {
    return __builtin_amdgcn_rcpf(1.f + __builtin_amdgcn_exp2f(a));
}
// full sigmoid for unscaled z (epilogue only)
__device__ __forceinline__ float sigm(float z) {
    return __builtin_amdgcn_rcpf(1.f + __builtin_amdgcn_exp2f(-LOG2E * z));
}

// 8 real batch rows per wave (cols 8-15 duplicate 0-7 via lane&7) -> 2048
// waves = 2 waves/SIMD: the second wave fills the first's RAW stalls in the
// serial layer chain. Per-wave VALU work is unchanged by the split (sigmoid
// ops are whole-register).
__global__ __launch_bounds__(256, 2) void mann_mfma(
    const float* __restrict__ x, const unsigned int* __restrict__ wstream,
    const float* __restrict__ Wout, const float* __restrict__ bout,
    float* __restrict__ out, int B, int L)
{
    __shared__ unsigned char lds[2 * CHUNK_BY];   // 40 KiB double buffer

    const int tid  = threadIdx.x;
    const int lane = tid & 63;
    const int c16  = lane & 15;     // batch column within fragment
    const int h    = lane >> 4;     // k-group / D-row group
    const int w    = (blockIdx.x * 256 + tid) >> 6;  // global wave id (0..2047)
    const int row  = w * 8 + (lane & 7);  // 8 real rows/wave, duplicated

    // ---- first-layer B fragment from x ----
    const float4 xa = *reinterpret_cast<const float4*>(x + (size_t)row * 20 + 4 * h);
    const float4 xb = *reinterpret_cast<const float4*>(x + (size_t)row * 20 + 16);
    short8 Bf = finalize_B(cvt_pk_bf16(xa.x, xa.y), cvt_pk_bf16(xa.z, xa.w),
                           cvt_pk_bf16(xb.x, xb.y), cvt_pk_bf16(xb.z, xb.w), h);

    // ---- chunk staging: global->reg early, reg->LDS late ----
    float4 sreg[V4_PER_T];
    auto stage_load = [&](int c) {
        const float4* g = reinterpret_cast<const float4*>(wstream) + (size_t)c * CHUNK_V4;
#pragma unroll
        for (int j = 0; j < V4_PER_T; ++j) sreg[j] = g[j * 256 + tid];
    };
    auto stage_write = [&](int bufi) {
        float4* d = reinterpret_cast<float4*>(lds + bufi * CHUNK_BY);
#pragma unroll
        for (int j = 0; j < V4_PER_T; ++j) d[j * 256 + tid] = sreg[j];
    };

    const unsigned lbase = (unsigned)(uintptr_t)&lds[0];

    stage_load(0); stage_write(0); __syncthreads();

    // A-fragment double buffer, filled by volatile ds_read (can't be sunk).
    short8 a0A, a1A, a0B, a1B;
    auto issue_A = [&](unsigned addr, short8& t0, short8& t1) {
        asm volatile("ds_read_b128 %0, %1 offset:0"    : "=v"(t0) : "v"(addr));
        asm volatile("ds_read_b128 %0, %1 offset:1024" : "=v"(t1) : "v"(addr));
    };
    issue_A(lbase + lane * 16, a0A, a1A);

    const f32x4 zero = {0.f, 0.f, 0.f, 0.f};
    float s0, s1, s2, s3, s4, s5, s6, s7;

    const int NC = L / CL;
    for (int c = 0; c < NC; ++c) {
        if (c + 1 < NC) stage_load(c + 1);           // global prefetch (vmcnt)
        const unsigned cb = lbase + (c & 1) * CHUNK_BY + lane * 16;
#pragma unroll
        for (int ll = 0; ll < CL; ++ll) {
            const bool even = (ll & 1) == 0;
            short8& c0 = even ? a0A : a0B;
            short8& c1 = even ? a1A : a1B;
            short8& n0 = even ? a0B : a0A;
            short8& n1 = even ? a1B : a1A;
            asm volatile("s_waitcnt lgkmcnt(0)" ::: "memory");  // cur landed
            __builtin_amdgcn_sched_barrier(0);                  // rule #18
            if (ll + 1 < CL) issue_A(cb + (ll + 1) * LAYER_BY, n0, n1);
            f32x4 acc0 = __builtin_amdgcn_mfma_f32_16x16x32_bf16(c0, Bf, zero, 0, 0, 0);
            f32x4 acc1 = __builtin_amdgcn_mfma_f32_16x16x32_bf16(c1, Bf, zero, 0, 0, 0);
            s0 = sigm_pre(acc0[0]); s1 = sigm_pre(acc0[1]);
            s2 = sigm_pre(acc0[2]); s3 = sigm_pre(acc0[3]);
            s4 = sigm_pre(acc1[0]); s5 = sigm_pre(acc1[1]);
            s6 = sigm_pre(acc1[2]); s7 = sigm_pre(acc1[3]);
            Bf = finalize_B(cvt_pk_bf16(s0, s1), cvt_pk_bf16(s2, s3),
                            cvt_pk_bf16(s4, s5), cvt_pk_bf16(s6, s7), h);
        }
        if (c + 1 < NC) {
            stage_write((c + 1) & 1);                // loads long since landed
            __syncthreads();
            issue_A(lbase + ((c + 1) & 1) * CHUNK_BY + lane * 16, a0A, a1A);
        }
    }

    // ---- epilogue ----
    const float4 woa = *reinterpret_cast<const float4*>(Wout + 4 * h);
    const float4 wob = *reinterpret_cast<const float4*>(Wout + 16);
    float part = s0 * woa.x + s1 * woa.y + s2 * woa.z + s3 * woa.w;
    const float m = (h == 0) ? 1.f : 0.f;
    part += m * (s4 * wob.x + s5 * wob.y + s6 * wob.z + s7 * wob.w);
    part += __shfl_xor(part, 16, 64);
    part += __shfl_xor(part, 32, 64);
    if (h == 0 && c16 < 8) out[row] = sigm(part + bout[0]);
}

extern "C" void kernel_launch(void* const* d_in, const int* in_sizes, int n_in,
                              void* d_out, int out_size, void* d_ws, size_t ws_size,
                              hipStream_t stream) {
    const float* x    = (const float*)d_in[0];
    const float* W    = (const float*)d_in[1];
    const float* b    = (const float*)d_in[2];
    const float* Wout = (const float*)d_in[3];
    const float* bout = (const float*)d_in[4];
    float* out = (float*)d_out;

    const int B = in_sizes[0] / 20;    // 16384
    const int L = in_sizes[1] / 400;   // 1000

    unsigned int* wstream = (unsigned int*)d_ws;   // L*2048 B = 2.05 MB

    prepack<<<L, 128, 0, stream>>>(W, b, wstream, L);

    const int grid = B / 32;           // 8 rows/wave, 4 waves/block -> 512 blocks
    mann_mfma<<<grid, 256, 0, stream>>>(x, wstream, Wout, bout, out, B, L);
}

// Round 8
// 278.411 us; speedup vs baseline: 1.2218x; 1.2218x over previous
//
#include <hip/hip_runtime.h>

#define LOG2E 1.44269504088896340736f

typedef __attribute__((ext_vector_type(8))) short short8;
typedef __attribute__((ext_vector_type(4))) float f32x4;
typedef __attribute__((ext_vector_type(2))) float f32x2;

constexpr int CL       = 10;              // layers per staged chunk
constexpr int LAYER_BY = 2048;            // bytes/layer: 2 tiles x 64 lanes x 16B
constexpr int CHUNK_BY = CL * LAYER_BY;   // 20480
constexpr int CHUNK_V4 = CHUNK_BY / 16;   // 1280 float4
constexpr int V4_PER_T = CHUNK_V4 / 256;  // 5 per thread

// k-slot -> logical input position (same map in prepack/A and runtime/B, so
// the HW k-order cancels). pos 20 carries bias (B supplies 1.0); pos>20 pad=0.
__device__ __forceinline__ int slot_pos(int h, int e) {
    return (e < 4) ? (4 * h + e) : (16 + 4 * h + (e - 4));
}

__device__ __forceinline__ unsigned short f32_to_bf16_rne(float f) {
    unsigned u = __builtin_bit_cast(unsigned, f);
    unsigned r = 0x7fffu + ((u >> 16) & 1u);
    return (unsigned short)((u + r) >> 16);
}

// One block per layer; 128 threads = 2 tiles x 64 lanes. Weights/bias are
// PRE-SCALED by 0.5: acc = 0.5*z = x, feeding the Pade sigmoid directly.
__global__ void prepack(const float* __restrict__ W, const float* __restrict__ b,
                        unsigned int* __restrict__ wstream, int L)
{
    const int l    = blockIdx.x;
    const int t    = threadIdx.x >> 6;
    const int lane = threadIdx.x & 63;
    const int n    = t * 16 + (lane & 15);   // output-neuron position
    const int h    = lane >> 4;
    unsigned int words[4];
#pragma unroll
    for (int d = 0; d < 4; ++d) {
        unsigned short halves[2];
#pragma unroll
        for (int half = 0; half < 2; ++half) {
            int e   = d * 2 + half;
            int pos = slot_pos(h, e);
            float v = 0.f;
            if (n < 20) {
                if (pos < 20)       v = W[(size_t)l * 400 + n * 20 + pos];
                else if (pos == 20) v = b[(size_t)l * 20 + n];
            }
            halves[half] = f32_to_bf16_rne(v * 0.5f);
        }
        words[d] = (unsigned)halves[0] | ((unsigned)halves[1] << 16);
    }
    unsigned int* dst = wstream + ((size_t)l * LAYER_BY + t * 1024 + lane * 16) / 4;
    dst[0] = words[0]; dst[1] = words[1]; dst[2] = words[2]; dst[3] = words[3];
}

__device__ __forceinline__ unsigned cvt_pk_bf16(float lo, float hi) {
    unsigned r;
    asm("v_cvt_pk_bf16_f32 %0, %1, %2" : "=v"(r) : "v"(lo), "v"(hi));
    return r;
}

// Mask pad slots: h==0 keeps real positions 16..19; h==1 slot e=4 is pos 20
// -> constant 1.0 (bias multiplier); other upper-half slots hit zero A columns.
__device__ __forceinline__ short8 finalize_B(unsigned p0, unsigned p1,
                                             unsigned p2, unsigned p3, int h) {
    if (h != 0) { p2 = (h == 1) ? 0x00003F80u : 0u; p3 = 0u; }
    union { unsigned u[4]; short8 s; } cv;
    cv.u[0] = p0; cv.u[1] = p1; cv.u[2] = p2; cv.u[3] = p3;
    return cv.s;
}

__device__ __forceinline__ f32x2 make2(float v) { f32x2 r; r.x = v; r.y = v; return r; }

// sigmoid(z) with x = 0.5*z already in acc (scale folded into weights):
// sigma = 0.5 + x*Ntil(u)/D(u), u = x^2 (tanh continued-fraction depth 5,
// Ntil = N/2). abs err <= ~2e-5 for |z|<=4, <= 1.2e-3 at |z|=8.
// All packed ops -> v_pk_{mul,add,fma}_f32; only rcp uses the trans pipe.
__device__ __forceinline__ f32x2 pade_sig(f32x2 x) {
    f32x2 u = x * x;
    f32x2 n = (u * make2(0.5f) + make2(52.5f)) * u + make2(472.5f);
    f32x2 d = (u * make2(15.0f) + make2(420.0f)) * u + make2(945.0f);
    f32x2 r;
    r.x = __builtin_amdgcn_rcpf(d.x);
    r.y = __builtin_amdgcn_rcpf(d.y);
    return (x * n) * r + make2(0.5f);
}

// full sigmoid for unscaled z (epilogue only, once)
__device__ __forceinline__ float sigm(float z) {
    return __builtin_amdgcn_rcpf(1.f + __builtin_amdgcn_exp2f(-LOG2E * z));
}

// 16 batch rows per wave via 16x16x32 MFMA; 1024 waves = 1/SIMD (structural).
__global__ __launch_bounds__(256, 1) void mann_mfma(
    const float* __restrict__ x, const unsigned int* __restrict__ wstream,
    const float* __restrict__ Wout, const float* __restrict__ bout,
    float* __restrict__ out, int B, int L)
{
    __shared__ unsigned char lds[2 * CHUNK_BY];   // 40 KiB double buffer

    const int tid  = threadIdx.x;
    const int lane = tid & 63;
    const int c16  = lane & 15;     // batch column within wave
    const int h    = lane >> 4;     // k-group / D-row group
    const int w    = (blockIdx.x * 256 + tid) >> 6;  // global wave id
    const int row  = w * 16 + c16;  // this lane's batch row

    // ---- first-layer B fragment from x ----
    const float4 xa = *reinterpret_cast<const float4*>(x + (size_t)row * 20 + 4 * h);
    const float4 xb = *reinterpret_cast<const float4*>(x + (size_t)row * 20 + 16);
    short8 Bf = finalize_B(cvt_pk_bf16(xa.x, xa.y), cvt_pk_bf16(xa.z, xa.w),
                           cvt_pk_bf16(xb.x, xb.y), cvt_pk_bf16(xb.z, xb.w), h);

    // ---- chunk staging: global->reg early, reg->LDS late ----
    float4 sreg[V4_PER_T];
    auto stage_load = [&](int c) {
        const float4* g = reinterpret_cast<const float4*>(wstream) + (size_t)c * CHUNK_V4;
#pragma unroll
        for (int j = 0; j < V4_PER_T; ++j) sreg[j] = g[j * 256 + tid];
    };
    auto stage_write = [&](int bufi) {
        float4* d = reinterpret_cast<float4*>(lds + bufi * CHUNK_BY);
#pragma unroll
        for (int j = 0; j < V4_PER_T; ++j) d[j * 256 + tid] = sreg[j];
    };

    const unsigned lbase = (unsigned)(uintptr_t)&lds[0];

    stage_load(0); stage_write(0); __syncthreads();

    // A-fragment double buffer, filled by volatile ds_read (can't be sunk).
    short8 a0A, a1A, a0B, a1B;
    auto issue_A = [&](unsigned addr, short8& t0, short8& t1) {
        asm volatile("ds_read_b128 %0, %1 offset:0"    : "=v"(t0) : "v"(addr));
        asm volatile("ds_read_b128 %0, %1 offset:1024" : "=v"(t1) : "v"(addr));
    };
    issue_A(lbase + lane * 16, a0A, a1A);

    const f32x4 zero = {0.f, 0.f, 0.f, 0.f};
    f32x2 q0, q1, q2, q3;

    const int NC = L / CL;
    for (int c = 0; c < NC; ++c) {
        if (c + 1 < NC) stage_load(c + 1);           // global prefetch (vmcnt)
        const unsigned cb = lbase + (c & 1) * CHUNK_BY + lane * 16;
#pragma unroll
        for (int ll = 0; ll < CL; ++ll) {
            const bool even = (ll & 1) == 0;
            short8& c0 = even ? a0A : a0B;
            short8& c1 = even ? a1A : a1B;
            short8& n0 = even ? a0B : a0A;
            short8& n1 = even ? a1B : a1A;
            asm volatile("s_waitcnt lgkmcnt(0)" ::: "memory");  // cur landed
            __builtin_amdgcn_sched_barrier(0);                  // rule #18
            if (ll + 1 < CL) issue_A(cb + (ll + 1) * LAYER_BY, n0, n1);
            f32x4 acc0 = __builtin_amdgcn_mfma_f32_16x16x32_bf16(c0, Bf, zero, 0, 0, 0);
            f32x4 acc1 = __builtin_amdgcn_mfma_f32_16x16x32_bf16(c1, Bf, zero, 0, 0, 0);
            q0.x = acc0[0]; q0.y = acc0[1];
            q1.x = acc0[2]; q1.y = acc0[3];
            q2.x = acc1[0]; q2.y = acc1[1];
            q3.x = acc1[2]; q3.y = acc1[3];
            q0 = pade_sig(q0); q1 = pade_sig(q1);
            q2 = pade_sig(q2); q3 = pade_sig(q3);
            Bf = finalize_B(cvt_pk_bf16(q0.x, q0.y), cvt_pk_bf16(q1.x, q1.y),
                            cvt_pk_bf16(q2.x, q2.y), cvt_pk_bf16(q3.x, q3.y), h);
        }
        if (c + 1 < NC) {
            stage_write((c + 1) & 1);                // loads long since landed
            __syncthreads();
            issue_A(lbase + ((c + 1) & 1) * CHUNK_BY + lane * 16, a0A, a1A);
        }
    }

    // ---- epilogue: lane (h,c16) holds neurons {4h+j} (q0,q1) and
    // {16+4h+j} (q2,q3; real only for h==0) ----
    const float4 woa = *reinterpret_cast<const float4*>(Wout + 4 * h);
    const float4 wob = *reinterpret_cast<const float4*>(Wout + 16);
    float part = q0.x * woa.x + q0.y * woa.y + q1.x * woa.z + q1.y * woa.w;
    const float m = (h == 0) ? 1.f : 0.f;
    part += m * (q2.x * wob.x + q2.y * wob.y + q3.x * wob.z + q3.y * wob.w);
    part += __shfl_xor(part, 16, 64);
    part += __shfl_xor(part, 32, 64);
    if (h == 0) out[row] = sigm(part + bout[0]);
}

extern "C" void kernel_launch(void* const* d_in, const int* in_sizes, int n_in,
                              void* d_out, int out_size, void* d_ws, size_t ws_size,
                              hipStream_t stream) {
    const float* x    = (const float*)d_in[0];
    const float* W    = (const float*)d_in[1];
    const float* b    = (const float*)d_in[2];
    const float* Wout = (const float*)d_in[3];
    const float* bout = (const float*)d_in[4];
    float* out = (float*)d_out;

    const int B = in_sizes[0] / 20;    // 16384
    const int L = in_sizes[1] / 400;   // 1000

    unsigned int* wstream = (unsigned int*)d_ws;   // L*2048 B = 2.05 MB

    prepack<<<L, 128, 0, stream>>>(W, b, wstream, L);

    const int grid = B / 64;           // 16 rows/wave, 4 waves/block
    mann_mfma<<<grid, 256, 0, stream>>>(x, wstream, Wout, bout, out, B, L);
}

// Round 9
// 272.169 us; speedup vs baseline: 1.2498x; 1.0229x over previous
//
#include <hip/hip_runtime.h>

#define LOG2E 1.44269504088896340736f

typedef __attribute__((ext_vector_type(8))) short short8;
typedef __attribute__((ext_vector_type(4))) float f32x4;
typedef __attribute__((ext_vector_type(2))) float f32x2;

constexpr int CL       = 20;              // layers per staged chunk
constexpr int LAYER_BY = 2048;            // bytes/layer: 2 tiles x 64 lanes x 16B
constexpr int CHUNK_BY = CL * LAYER_BY;   // 40960
constexpr int CHUNK_V4 = CHUNK_BY / 16;   // 2560 float4
constexpr int V4_PER_T = CHUNK_V4 / 256;  // 10 per thread

// k-slot -> logical input position (same map in prepack/A and runtime/B, so
// the HW k-order cancels). pos 20 carries bias (B supplies 1.0); pos>20 pad=0.
__device__ __forceinline__ int slot_pos(int h, int e) {
    return (e < 4) ? (4 * h + e) : (16 + 4 * h + (e - 4));
}

__device__ __forceinline__ unsigned short f32_to_bf16_rne(float f) {
    unsigned u = __builtin_bit_cast(unsigned, f);
    unsigned r = 0x7fffu + ((u >> 16) & 1u);
    return (unsigned short)((u + r) >> 16);
}

// One block per layer; 128 threads = 2 tiles x 64 lanes. Weights/bias are
// PRE-SCALED by 0.5: acc = 0.5*z = x, feeding the Pade sigmoid directly.
__global__ void prepack(const float* __restrict__ W, const float* __restrict__ b,
                        unsigned int* __restrict__ wstream, int L)
{
    const int l    = blockIdx.x;
    const int t    = threadIdx.x >> 6;
    const int lane = threadIdx.x & 63;
    const int n    = t * 16 + (lane & 15);   // output-neuron position
    const int h    = lane >> 4;
    unsigned int words[4];
#pragma unroll
    for (int d = 0; d < 4; ++d) {
        unsigned short halves[2];
#pragma unroll
        for (int half = 0; half < 2; ++half) {
            int e   = d * 2 + half;
            int pos = slot_pos(h, e);
            float v = 0.f;
            if (n < 20) {
                if (pos < 20)       v = W[(size_t)l * 400 + n * 20 + pos];
                else if (pos == 20) v = b[(size_t)l * 20 + n];
            }
            halves[half] = f32_to_bf16_rne(v * 0.5f);
        }
        words[d] = (unsigned)halves[0] | ((unsigned)halves[1] << 16);
    }
    unsigned int* dst = wstream + ((size_t)l * LAYER_BY + t * 1024 + lane * 16) / 4;
    dst[0] = words[0]; dst[1] = words[1]; dst[2] = words[2]; dst[3] = words[3];
}

__device__ __forceinline__ unsigned cvt_pk_bf16(float lo, float hi) {
    unsigned r;
    asm("v_cvt_pk_bf16_f32 %0, %1, %2" : "=v"(r) : "v"(lo), "v"(hi));
    return r;
}

// Mask pad slots: h==0 keeps real positions 16..19; h==1 slot e=4 is pos 20
// -> constant 1.0 (bias multiplier); other upper-half slots hit zero A columns.
__device__ __forceinline__ short8 finalize_B(unsigned p0, unsigned p1,
                                             unsigned p2, unsigned p3, int h) {
    if (h != 0) { p2 = (h == 1) ? 0x00003F80u : 0u; p3 = 0u; }
    union { unsigned u[4]; short8 s; } cv;
    cv.u[0] = p0; cv.u[1] = p1; cv.u[2] = p2; cv.u[3] = p3;
    return cv.s;
}

__device__ __forceinline__ f32x2 make2(float v) { f32x2 r; r.x = v; r.y = v; return r; }

// sigmoid(z) with x = 0.5*z already in acc: sigma = 0.5 + x*Ntil(u)/D(u),
// u = x^2. abs err <= ~2e-5 for |z|<=4, <= 1.2e-3 at |z|=8. Packed f32 ops.
__device__ __forceinline__ f32x2 pade_sig(f32x2 x) {
    f32x2 u = x * x;
    f32x2 n = (u * make2(0.5f) + make2(52.5f)) * u + make2(472.5f);
    f32x2 d = (u * make2(15.0f) + make2(420.0f)) * u + make2(945.0f);
    f32x2 r;
    r.x = __builtin_amdgcn_rcpf(d.x);
    r.y = __builtin_amdgcn_rcpf(d.y);
    return (x * n) * r + make2(0.5f);
}

// full sigmoid for unscaled z (epilogue only, once)
__device__ __forceinline__ float sigm(float z) {
    return __builtin_amdgcn_rcpf(1.f + __builtin_amdgcn_exp2f(-LOG2E * z));
}

// Issue both A-fragment reads for one layer (volatile -> cannot be sunk).
__device__ __forceinline__ void issue_frag(unsigned addr, short8& t0, short8& t1) {
    asm volatile("ds_read_b128 %0, %1 offset:0"    : "=v"(t0) : "v"(addr));
    asm volatile("ds_read_b128 %0, %1 offset:1024" : "=v"(t1) : "v"(addr));
}

__device__ __forceinline__ void layer_step(const short8& c0, const short8& c1,
                                           short8& Bf, f32x2& q0, f32x2& q1,
                                           f32x2& q2, f32x2& q3, int h) {
    const f32x4 zero = {0.f, 0.f, 0.f, 0.f};
    f32x4 acc0 = __builtin_amdgcn_mfma_f32_16x16x32_bf16(c0, Bf, zero, 0, 0, 0);
    f32x4 acc1 = __builtin_amdgcn_mfma_f32_16x16x32_bf16(c1, Bf, zero, 0, 0, 0);
    q0.x = acc0[0]; q0.y = acc0[1];
    q1.x = acc0[2]; q1.y = acc0[3];
    q2.x = acc1[0]; q2.y = acc1[1];
    q3.x = acc1[2]; q3.y = acc1[3];
    q0 = pade_sig(q0); q1 = pade_sig(q1);
    q2 = pade_sig(q2); q3 = pade_sig(q3);
    Bf = finalize_B(cvt_pk_bf16(q0.x, q0.y), cvt_pk_bf16(q1.x, q1.y),
                    cvt_pk_bf16(q2.x, q2.y), cvt_pk_bf16(q3.x, q3.y), h);
}

// 16 batch rows per wave via 16x16x32 MFMA; 1024 waves = 1/SIMD (structural).
// A-fragments prefetched 2 LAYERS ahead (4 named buffers, counted lgkmcnt(2)
// waits) so the ds_read latency is fully covered by ~2 layers of compute.
__global__ __launch_bounds__(256, 1) void mann_mfma(
    const float* __restrict__ x, const unsigned int* __restrict__ wstream,
    const float* __restrict__ Wout, const float* __restrict__ bout,
    float* __restrict__ out, int B, int L)
{
    __shared__ unsigned char lds[2 * CHUNK_BY];   // 80 KiB double buffer

    const int tid  = threadIdx.x;
    const int lane = tid & 63;
    const int c16  = lane & 15;     // batch column within wave
    const int h    = lane >> 4;     // k-group / D-row group
    const int w    = (blockIdx.x * 256 + tid) >> 6;  // global wave id
    const int row  = w * 16 + c16;  // this lane's batch row

    // ---- first-layer B fragment from x ----
    const float4 xa = *reinterpret_cast<const float4*>(x + (size_t)row * 20 + 4 * h);
    const float4 xb = *reinterpret_cast<const float4*>(x + (size_t)row * 20 + 16);
    short8 Bf = finalize_B(cvt_pk_bf16(xa.x, xa.y), cvt_pk_bf16(xa.z, xa.w),
                           cvt_pk_bf16(xb.x, xb.y), cvt_pk_bf16(xb.z, xb.w), h);

    // ---- chunk staging: global->reg early, reg->LDS late ----
    float4 sreg[V4_PER_T];
    auto stage_load = [&](int c) {
        const float4* g = reinterpret_cast<const float4*>(wstream) + (size_t)c * CHUNK_V4;
#pragma unroll
        for (int j = 0; j < V4_PER_T; ++j) sreg[j] = g[j * 256 + tid];
    };
    auto stage_write = [&](int bufi) {
        float4* d = reinterpret_cast<float4*>(lds + bufi * CHUNK_BY);
#pragma unroll
        for (int j = 0; j < V4_PER_T; ++j) d[j * 256 + tid] = sreg[j];
    };

    const unsigned lbase = (unsigned)(uintptr_t)&lds[0];

    stage_load(0); stage_write(0); __syncthreads();

    // 4 named A-fragment buffers; buf[l & 3] holds layer l's fragments.
    short8 f0a, f0b, f1a, f1b, f2a, f2b, f3a, f3b;

    const unsigned cb0 = lbase + lane * 16;
    issue_frag(cb0,            f0a, f0b);   // layer 0
    issue_frag(cb0 + LAYER_BY, f1a, f1b);   // layer 1

    f32x2 q0, q1, q2, q3;

    const int NC = L / CL;   // 50
    for (int c = 0; c < NC; ++c) {
        if (c + 1 < NC) stage_load(c + 1);           // global prefetch (vmcnt)
        const unsigned cb = lbase + (c & 1) * CHUNK_BY + lane * 16;
#pragma unroll
        for (int ll = 0; ll < CL; ++ll) {
            // Counted wait: 4 reads outstanding (ll, ll+1); wait oldest 2.
            if (ll == CL - 1) asm volatile("s_waitcnt lgkmcnt(0)");
            else              asm volatile("s_waitcnt lgkmcnt(2)");
            __builtin_amdgcn_sched_barrier(0);       // rule #18
            if (ll + 2 < CL) {
                const unsigned a = cb + (ll + 2) * LAYER_BY;
                const int bi = (ll + 2) & 3;
                if      (bi == 0) issue_frag(a, f0a, f0b);
                else if (bi == 1) issue_frag(a, f1a, f1b);
                else if (bi == 2) issue_frag(a, f2a, f2b);
                else              issue_frag(a, f3a, f3b);
            }
            __builtin_amdgcn_sched_barrier(0);
            const int ci = ll & 3;
            if      (ci == 0) layer_step(f0a, f0b, Bf, q0, q1, q2, q3, h);
            else if (ci == 1) layer_step(f1a, f1b, Bf, q0, q1, q2, q3, h);
            else if (ci == 2) layer_step(f2a, f2b, Bf, q0, q1, q2, q3, h);
            else              layer_step(f3a, f3b, Bf, q0, q1, q2, q3, h);
        }
        if (c + 1 < NC) {
            stage_write((c + 1) & 1);                // loads long since landed
            __syncthreads();
            const unsigned nb = lbase + ((c + 1) & 1) * CHUNK_BY + lane * 16;
            issue_frag(nb,            f0a, f0b);     // next chunk layer 0
            issue_frag(nb + LAYER_BY, f1a, f1b);     // next chunk layer 1
        }
    }

    // ---- epilogue: lane (h,c16) holds neurons {4h+j} (q0,q1) and
    // {16+4h+j} (q2,q3; real only for h==0) ----
    const float4 woa = *reinterpret_cast<const float4*>(Wout + 4 * h);
    const float4 wob = *reinterpret_cast<const float4*>(Wout + 16);
    float part = q0.x * woa.x + q0.y * woa.y + q1.x * woa.z + q1.y * woa.w;
    const float m = (h == 0) ? 1.f : 0.f;
    part += m * (q2.x * wob.x + q2.y * wob.y + q3.x * wob.z + q3.y * wob.w);
    part += __shfl_xor(part, 16, 64);
    part += __shfl_xor(part, 32, 64);
    if (h == 0) out[row] = sigm(part + bout[0]);
}

extern "C" void kernel_launch(void* const* d_in, const int* in_sizes, int n_in,
                              void* d_out, int out_size, void* d_ws, size_t ws_size,
                              hipStream_t stream) {
    const float* x    = (const float*)d_in[0];
    const float* W    = (const float*)d_in[1];
    const float* b    = (const float*)d_in[2];
    const float* Wout = (const float*)d_in[3];
    const float* bout = (const float*)d_in[4];
    float* out = (float*)d_out;

    const int B = in_sizes[0] / 20;    // 16384
    const int L = in_sizes[1] / 400;   // 1000

    unsigned int* wstream = (unsigned int*)d_ws;   // L*2048 B = 2.05 MB

    prepack<<<L, 128, 0, stream>>>(W, b, wstream, L);

    const int grid = B / 64;           // 16 rows/wave, 4 waves/block
    mann_mfma<<<grid, 256, 0, stream>>>(x, wstream, Wout, bout, out, B, L);
}